// Round 8
// baseline (19095.590 us; speedup 1.0000x reference)
//
#include <hip/hip_runtime.h>
#include <cstdint>

#define BB 128
#define SS 1024
#define HH 256
#define GG 768
#define CC 64                      // chunk length (timesteps)
#define NC (SS / CC)               // 16 chunks
#define LOG2E 1.44269504088896340736f

typedef __attribute__((ext_vector_type(8))) __bf16 bf16x8;
typedef __attribute__((ext_vector_type(4))) __bf16 bf16x4;
typedef __attribute__((ext_vector_type(4))) float f32x4;

static __device__ __forceinline__ f32x4 mfma16(bf16x8 a, bf16x8 b, f32x4 c) {
    return __builtin_amdgcn_mfma_f32_16x16x32_bf16(a, b, c, 0, 0, 0);
}

static __device__ __forceinline__ bf16x8 load_w8(const float* __restrict__ p) {
    f32x4 a = *(const f32x4*)p;
    f32x4 b = *(const f32x4*)(p + 4);
    bf16x8 v;
    v[0] = (__bf16)a[0]; v[1] = (__bf16)a[1]; v[2] = (__bf16)a[2]; v[3] = (__bf16)a[3];
    v[4] = (__bf16)b[0]; v[5] = (__bf16)b[1]; v[6] = (__bf16)b[2]; v[7] = (__bf16)b[3];
    return v;
}

// LDS-only barrier (global ops keep floating) / full-drain barrier
#define LBAR() asm volatile("s_waitcnt lgkmcnt(0)\n\ts_barrier" ::: "memory")
#define VBAR() asm volatile("s_waitcnt vmcnt(0) lgkmcnt(0)\n\ts_barrier" ::: "memory")
// once-per-chunk coherence (h0 handoff only)
#define FENCE_ACQ() __builtin_amdgcn_fence(__ATOMIC_ACQUIRE, "agent")
#define FENCE_REL() __builtin_amdgcn_fence(__ATOMIC_RELEASE, "agent")

static __device__ __forceinline__ int ldflag(int* p) {
    return __hip_atomic_load(p, __ATOMIC_RELAXED, __HIP_MEMORY_SCOPE_AGENT);
}
static __device__ __forceinline__ void wait_ge(int* p, int need) {
    int v = ldflag(p);
    while (v < need) {
        __builtin_amdgcn_s_sleep(8);
        v = ldflag(p);
    }
}
static __device__ __forceinline__ void publish(int* p, int v) {
    __hip_atomic_store(p, v, __ATOMIC_RELAXED, __HIP_MEMORY_SCOPE_AGENT);
}

// wave w holds W_hh tiles w+8j: j=0..3 in VGPR, j=4,5 staged to LDS
static __device__ __forceinline__ void load_wfrags(
    const float* __restrict__ W, char* wlds, bf16x8 (&wf)[4][8],
    int w, int l, int c, int q)
{
#pragma unroll
    for (int j = 0; j < 4; ++j) {
        const float* wp = W + (size_t)((w + 8 * j) * 16 + c) * HH + q * 8;
#pragma unroll
        for (int kf = 0; kf < 8; ++kf) wf[j][kf] = load_w8(wp + kf * 32);
    }
#pragma unroll
    for (int j = 4; j < 6; ++j) {
        const float* wp = W + (size_t)((w + 8 * j) * 16 + c) * HH + q * 8;
#pragma unroll
        for (int kf = 0; kf < 8; ++kf) {
            bf16x8 v = load_w8(wp + kf * 32);
            *(bf16x8*)(wlds + (((w * 2 + (j - 4)) * 8 + kf) << 10) + l * 16) = v;
        }
    }
}

// 48 MFMAs/wave over K=256 from swizzled LDS B-buffer (8 rows x 256 bf16)
static __device__ __forceinline__ void gemm6(
    f32x4 (&acc)[6], const char* bsrc, const char* wlds,
    const bf16x8 (&wf)[4][8], int w, int l, int q, int b8)
{
#pragma unroll
    for (int kh = 0; kh < 2; ++kh) {
        bf16x8 hb[4];
#pragma unroll
        for (int kf = 0; kf < 4; ++kf) {
            int k0 = kh * 128 + kf * 32 + q * 8;
            hb[kf] = *(const bf16x8*)(bsrc + b8 * 512 + ((2 * k0) ^ (b8 << 4)));
        }
#pragma unroll
        for (int j = 0; j < 4; ++j)
#pragma unroll
            for (int kf = 0; kf < 4; ++kf)
                acc[j] = mfma16(wf[j][kh * 4 + kf], hb[kf], acc[j]);
#pragma unroll
        for (int j = 4; j < 6; ++j)
#pragma unroll
            for (int kf = 0; kf < 4; ++kf) {
                bf16x8 a = *(const bf16x8*)(wlds +
                    (((w * 2 + (j - 4)) * 8 + kh * 4 + kf) << 10) + l * 16);
                acc[j] = mfma16(a, hb[kf], acc[j]);
            }
    }
}

// ---------------------------------------------------------------------------
// 2-stage fused pipeline. 32 WGs x 512 thr: layer = bid>>4, g = bid&15.
// Each WG per 64-step chunk: (a) bulk ih GEMM (W_ih streamed, 16 real
// B-cols = 2 steps x 8 batches per iter) -> PRIVATE per-WG global scratch
// (same-XCD L2, plain ops); (b) rec scan reading own scratch. Only
// cross-CU dep: L0's Y(h0) chunk -> L1, fenced once per chunk.
// ---------------------------------------------------------------------------
__global__ __launch_bounds__(512, 2) void k_fused(
    const float* __restrict__ x, const float* __restrict__ hx,
    const float* __restrict__ W_ih, const float* __restrict__ W_hh,
    const float* __restrict__ gamma, const float* __restrict__ beta,
    float* __restrict__ Y, char* __restrict__ ws)
{
    extern __shared__ __align__(16) char lds[];
    char*  wlds = lds;                    // 131072: W_hh tiles j=4,5
    char*  hbuf = lds + 131072;           // 4096: h[8][256] bf16 swz
    float* part = (float*)(lds + 135168); // 1920
    float* gb   = (float*)(lds + 137088); // 6144 -> 143232
    char*  xst  = lds + 143232;           // 8192: 16 rows x 512B swz -> 151424

    const int bid = blockIdx.x;
    const int layer = bid >> 4;
    const int g = bid & 15;

    __bf16* scr = (__bf16*)(ws + ((size_t)bid << 20));   // 786KB used of 1MB
    int* flg = (int*)(ws + (128u << 20)) + g * 32;       // L0->L1 chunk count

    const int tid = threadIdx.x;
    const int w = tid >> 6, l = tid & 63;
    const int c = l & 15, q = l >> 4;
    const int b8 = c & 7, chi = c >> 3;

    const float* gmm = gamma + (size_t)layer * GG;
    const float* bta = beta + (size_t)layer * GG;
    const float* hx0 = hx + (size_t)layer * BB * HH;
    const float* Wih = W_ih + (size_t)layer * GG * HH;
    const float* in  = layer ? (const float*)Y : x;

    for (int idx = tid; idx < GG; idx += 512) {
        float sc = (idx >= 512) ? (-2.0f * LOG2E) : (-LOG2E);
        gb[idx]      = gmm[idx] * sc;
        gb[GG + idx] = bta[idx] * sc;
    }
    for (int idx = tid; idx < 8 * HH; idx += 512) {
        int b = idx >> 8, kk = idx & 255;
        *(__bf16*)(hbuf + b * 512 + ((2 * kk) ^ ((b & 7) << 4))) =
            (__bf16)hx0[(size_t)(g * 8 + b) * HH + kk];
    }
    bf16x8 wf[4][8];
    load_wfrags(W_hh + (size_t)layer * GG * HH, wlds, wf, w, l, c, q);
    __syncthreads();

    const int o0base = (w + 8 * chi) * 16 + q * 4;
    const int ho = w * 16 + chi * 128 + q * 4;
    float* yb = Y + (size_t)(g * 8 + b8) * SS * HH;

#pragma unroll 1
    for (int k = 0; k < NC; ++k) {
        if (layer) { wait_ge(flg, k + 1); FENCE_ACQ(); }
        const int t0 = k * CC;

        // ============ bulk ih phase: 32 iters x 2 steps ============
#pragma unroll 1
        for (int it = 0; it < CC / 2; ++it) {
            const int tq = t0 + it * 2;
            // stage 2 steps x 8 batches x 256 -> xst rows (s*8+b)
#pragma unroll
            for (int v = 0; v < 2; ++v) {
                int e = tid + v * 512;
                int row = e >> 6, kc = (e & 63) * 4;
                f32x4 xv = *(const f32x4*)(in +
                    ((size_t)(g * 8 + (row & 7)) * SS + tq + (row >> 3)) * HH + kc);
                bf16x4 o;
#pragma unroll
                for (int r = 0; r < 4; ++r) o[r] = (__bf16)xv[r];
                *(bf16x4*)(xst + row * 512 + ((2 * kc) ^ ((row & 7) << 4))) = o;
            }
            LBAR();
            f32x4 acc[6];
#pragma unroll
            for (int j = 0; j < 6; ++j) acc[j] = (f32x4){0.f, 0.f, 0.f, 0.f};
#pragma unroll
            for (int kh = 0; kh < 2; ++kh) {
                bf16x8 hb[4];
#pragma unroll
                for (int kf = 0; kf < 4; ++kf) {
                    int k0 = kh * 128 + kf * 32 + q * 8;
                    hb[kf] = *(const bf16x8*)(xst + c * 512 + ((2 * k0) ^ ((c & 7) << 4)));
                }
#pragma unroll
                for (int j = 0; j < 6; ++j)
#pragma unroll
                    for (int kf = 0; kf < 4; ++kf) {
                        bf16x8 a = load_w8(Wih +
                            (size_t)((w + 8 * j) * 16 + c) * HH + (kh * 4 + kf) * 32 + q * 8);
                        acc[j] = mfma16(a, hb[kf], acc[j]);
                    }
            }
            // store: lane c -> (step tq+(c>>3), batch c&7), rows q*4..+3
            {
                int ts = it * 2 + (c >> 3);          // 0..63 within chunk
                int bs = c & 7;
#pragma unroll
                for (int j = 0; j < 6; ++j) {
                    bf16x4 o;
#pragma unroll
                    for (int r = 0; r < 4; ++r) o[r] = (__bf16)acc[j][r];
                    *(bf16x4*)(scr + (size_t)(ts * 48 + w + 8 * j) * 128 + bs * 16 + q * 4) = o;
                }
            }
            LBAR();                                  // protect xst
        }
        VBAR();                                      // scratch visible via own L2

        // ============ rec phase: 64 steps ============
        bf16x4 ihc[3], ihn[3];
#pragma unroll
        for (int j2 = 0; j2 < 3; ++j2)
            ihc[j2] = *(const bf16x4*)(scr +
                (size_t)(0 * 48 + w + 8 * chi + 16 * j2) * 128 + b8 * 16 + q * 4);

#pragma unroll 1
        for (int tt = 0; tt < CC; ++tt) {
            const int t = t0 + tt;
            if (tt + 1 < CC) {
#pragma unroll
                for (int j2 = 0; j2 < 3; ++j2)
                    ihn[j2] = *(const bf16x4*)(scr +
                        (size_t)((tt + 1) * 48 + w + 8 * chi + 16 * j2) * 128 + b8 * 16 + q * 4);
            }

            f32x4 acc[6];
#pragma unroll
            for (int j = 0; j < 6; ++j) acc[j] = (f32x4){0.f, 0.f, 0.f, 0.f};
            gemm6(acc, hbuf, wlds, wf, w, l, q, b8);

            // B-cols c and c^8 duplicate -> odd tiles already in acc[2j2+1]
            f32x4 pa[3];
#pragma unroll
            for (int j2 = 0; j2 < 3; ++j2)
                pa[j2] = chi ? acc[2 * j2 + 1] : acc[2 * j2];

            // r,z stats
            float s0 = 0.f, t0s = 0.f, s1 = 0.f, t1 = 0.f;
#pragma unroll
            for (int r = 0; r < 4; ++r) {
                float p0 = pa[0][r] + (float)ihc[0][r]; pa[0][r] = p0; s0 += p0; t0s += p0 * p0;
                float p1 = pa[1][r] + (float)ihc[1][r]; pa[1][r] = p1; s1 += p1; t1 += p1 * p1;
            }
            s0 += __shfl_xor(s0, 16); t0s += __shfl_xor(t0s, 16);
            s0 += __shfl_xor(s0, 32); t0s += __shfl_xor(t0s, 32);
            s0 += __shfl_xor(s0, 8);  t0s += __shfl_xor(t0s, 8);
            s1 += __shfl_xor(s1, 16); t1 += __shfl_xor(t1, 16);
            s1 += __shfl_xor(s1, 32); t1 += __shfl_xor(t1, 32);
            s1 += __shfl_xor(s1, 8);  t1 += __shfl_xor(t1, 8);
            if (l < 8) {
                *(float2*)(part + (0 * 8 + l) * 20 + w * 2) = make_float2(s0, t0s);
                *(float2*)(part + (1 * 8 + l) * 20 + w * 2) = make_float2(s1, t1);
            }
            LBAR();  // BAR1

            float2 mrz[2];
#pragma unroll
            for (int gg = 0; gg < 2; ++gg) {
                const f32x4* pp = (const f32x4*)(part + (gg * 8 + b8) * 20);
                f32x4 a = pp[0] + pp[1] + pp[2] + pp[3];
                float S = a[0] + a[2], Q2 = a[1] + a[3];
                float m = S * (1.f / 256.f);
                float v = Q2 * (1.f / 256.f) - m * m;
                mrz[gg] = make_float2(m, __builtin_amdgcn_rsqf(v + 1e-5f));
            }

            float rz[2][4];
#pragma unroll
            for (int gg = 0; gg < 2; ++gg) {
                int o0 = o0base + gg * 256;
                f32x4 gam = *(f32x4*)(gb + o0);
                f32x4 bet = *(f32x4*)(gb + GG + o0);
#pragma unroll
                for (int r = 0; r < 4; ++r) {
                    float sf = mrz[gg].y * gam[r];
                    float y  = pa[gg][r] * sf + (bet[r] - mrz[gg].x * sf);
                    rz[gg][r] = __builtin_amdgcn_rcpf(1.f + __builtin_amdgcn_exp2f(y));
                }
            }

            float pn[4]; float sn = 0.f, tn2 = 0.f;
#pragma unroll
            for (int r = 0; r < 4; ++r) {
                float p = (float)ihc[2][r] + rz[0][r] * pa[2][r];
                pn[r] = p; sn += p; tn2 += p * p;
            }
            sn += __shfl_xor(sn, 16); tn2 += __shfl_xor(tn2, 16);
            sn += __shfl_xor(sn, 32); tn2 += __shfl_xor(tn2, 32);
            sn += __shfl_xor(sn, 8);  tn2 += __shfl_xor(tn2, 8);
            if (l < 8)
                *(float2*)(part + (2 * 8 + l) * 20 + w * 2) = make_float2(sn, tn2);
            LBAR();  // BAR2

            {
                const f32x4* pp = (const f32x4*)(part + (2 * 8 + b8) * 20);
                f32x4 a = pp[0] + pp[1] + pp[2] + pp[3];
                float S = a[0] + a[2], Q2 = a[1] + a[3];
                float m = S * (1.f / 256.f);
                float v = Q2 * (1.f / 256.f) - m * m;
                float rs = __builtin_amdgcn_rsqf(v + 1e-5f);

                int o0 = o0base + 512;
                f32x4 gam = *(f32x4*)(gb + o0);
                f32x4 bet = *(f32x4*)(gb + GG + o0);
                char* haddr = hbuf + b8 * 512 + ((2 * ho) ^ (b8 << 4));
                bf16x4 hov = *(bf16x4*)haddr;
                f32x4 yv; bf16x4 hnv;
#pragma unroll
                for (int r = 0; r < 4; ++r) {
                    float sf = rs * gam[r];
                    float y  = pn[r] * sf + (bet[r] - m * sf);
                    float nh = 2.f * __builtin_amdgcn_rcpf(1.f + __builtin_amdgcn_exp2f(y)) - 1.f;
                    float hn = nh + rz[1][r] * ((float)hov[r] - nh);
                    yv[r] = hn; hnv[r] = (__bf16)hn;
                }
                *(bf16x4*)haddr = hnv;
                *(f32x4*)(yb + (size_t)t * HH + ho) = yv;  // plain, drained per chunk
            }
            if (tt + 1 < CC) {
#pragma unroll
                for (int j2 = 0; j2 < 3; ++j2) ihc[j2] = ihn[j2];
            }
            LBAR();  // BAR3 (protect hbuf for next gemm)
        }

        // chunk boundary: hand h0 chunk to L1 (L0 only; L1's Y is final out)
        VBAR();
        if (!layer) {
            FENCE_REL();
            if (tid == 0) publish(flg, k + 1);
        }
    }
}

// ---------------------------------------------------------------------------
extern "C" void kernel_launch(void* const* d_in, const int* in_sizes, int n_in,
                              void* d_out, int out_size, void* d_ws, size_t ws_size,
                              hipStream_t stream)
{
    (void)in_sizes; (void)n_in; (void)out_size;
    const float* x    = (const float*)d_in[0];
    const float* hx   = (const float*)d_in[1];
    const float* W_ih = (const float*)d_in[2];
    const float* W_hh = (const float*)d_in[3];
    const float* gmm  = (const float*)d_in[4];
    const float* bta  = (const float*)d_in[5];
    float* Y = (float*)d_out;
    char* ws = (char*)d_ws;

    // ws: per-WG ih scratch 32 x 1MiB [0,32MiB); flags at 128MiB
    if (ws_size < (size_t)SS * BB * GG * 2) return;

    hipFuncSetAttribute((const void*)k_fused,
                        hipFuncAttributeMaxDynamicSharedMemorySize, 151424);

    hipMemsetAsync(ws + (128u << 20), 0, 64 * 32 * 4, stream);

    k_fused<<<dim3(32), dim3(512), 151424, stream>>>(
        x, hx, W_ih, W_hh, gmm, bta, Y, ws);
}

// Round 9
// 4875.394 us; speedup vs baseline: 3.9167x; 3.9167x over previous
//
#include <hip/hip_runtime.h>
#include <cstdint>

#define BB 128
#define SS 1024
#define HH 256
#define GG 768
#define CC 64                      // chunk length (timesteps)
#define NC (SS / CC)               // 16 chunks
#define DD 128                     // ring depth in slots = 2 chunks
#define LOG2E 1.44269504088896340736f

typedef __attribute__((ext_vector_type(8))) __bf16 bf16x8;
typedef __attribute__((ext_vector_type(4))) __bf16 bf16x4;
typedef __attribute__((ext_vector_type(4))) float f32x4;
typedef unsigned long long u64;

static __device__ __forceinline__ f32x4 mfma16(bf16x8 a, bf16x8 b, f32x4 c) {
    return __builtin_amdgcn_mfma_f32_16x16x32_bf16(a, b, c, 0, 0, 0);
}

static __device__ __forceinline__ bf16x8 load_w8(const float* __restrict__ p) {
    f32x4 a = *(const f32x4*)p;
    f32x4 b = *(const f32x4*)(p + 4);
    bf16x8 v;
    v[0] = (__bf16)a[0]; v[1] = (__bf16)a[1]; v[2] = (__bf16)a[2]; v[3] = (__bf16)a[3];
    v[4] = (__bf16)b[0]; v[5] = (__bf16)b[1]; v[6] = (__bf16)b[2]; v[7] = (__bf16)b[3];
    return v;
}

// LDS-only barrier (global ops keep floating) / full-drain barrier
#define LBAR() asm volatile("s_waitcnt lgkmcnt(0)\n\ts_barrier" ::: "memory")
#define VBAR() asm volatile("s_waitcnt vmcnt(0) lgkmcnt(0)\n\ts_barrier" ::: "memory")
// cross-XCD coherence ops (only taken when producer/consumer XCDs differ)
#define FENCE_ACQ() __builtin_amdgcn_fence(__ATOMIC_ACQUIRE, "agent")
#define FENCE_REL() __builtin_amdgcn_fence(__ATOMIC_RELEASE, "agent")

// own XCD id (wave-uniform; all waves of a WG share one CU -> one XCD)
static __device__ __forceinline__ int get_xcc() {
    int v;
    asm volatile("s_getreg_b32 %0, hwreg(HW_REG_XCC_ID)" : "=s"(v));
    return v & 15;
}

// volatile (sc0) 8B load: bypasses L1, reads the XCD-shared L2
static __device__ __forceinline__ u64 vld8(const u64* p) {
    return *(volatile const u64*)p;
}

// ring element offset: slot-major, tile T=0..47, 8 batches x 16 outs
static __device__ __forceinline__ size_t ring_off(int t, int g, int T, int b8, int o) {
    return (((size_t)(t & (DD - 1)) * 16 + g) * 48 + T) * 128 + b8 * 16 + o;
}

static __device__ __forceinline__ int ldflag(int* p) {
    return __hip_atomic_load(p, __ATOMIC_RELAXED, __HIP_MEMORY_SCOPE_AGENT);
}
static __device__ __forceinline__ int wait_ge(int* p, int need) {
    int v = ldflag(p);
    while (v < need) {
        __builtin_amdgcn_s_sleep(8);
        v = ldflag(p);
    }
    return v;
}
static __device__ __forceinline__ void publish(int* p, int v) {
    __hip_atomic_store(p, v, __ATOMIC_RELAXED, __HIP_MEMORY_SCOPE_AGENT);
}

// wave w holds W tiles w+8j: j=0..3 in VGPR, j=4,5 staged to LDS
static __device__ __forceinline__ void load_wfrags(
    const float* __restrict__ W, char* wlds, bf16x8 (&wf)[4][8],
    int w, int l, int c, int q)
{
#pragma unroll
    for (int j = 0; j < 4; ++j) {
        const float* wp = W + (size_t)((w + 8 * j) * 16 + c) * HH + q * 8;
#pragma unroll
        for (int kf = 0; kf < 8; ++kf) wf[j][kf] = load_w8(wp + kf * 32);
    }
#pragma unroll
    for (int j = 4; j < 6; ++j) {
        const float* wp = W + (size_t)((w + 8 * j) * 16 + c) * HH + q * 8;
#pragma unroll
        for (int kf = 0; kf < 8; ++kf) {
            bf16x8 v = load_w8(wp + kf * 32);
            *(bf16x8*)(wlds + (((w * 2 + (j - 4)) * 8 + kf) << 10) + l * 16) = v;
        }
    }
}

// 48 MFMAs/wave over K=256 from swizzled LDS B-buffer (8 rows x 256 bf16)
static __device__ __forceinline__ void gemm6(
    f32x4 (&acc)[6], const char* bsrc, const char* wlds,
    const bf16x8 (&wf)[4][8], int w, int l, int q, int b8)
{
#pragma unroll
    for (int kh = 0; kh < 2; ++kh) {
        bf16x8 hb[4];
#pragma unroll
        for (int kf = 0; kf < 4; ++kf) {
            int k0 = kh * 128 + kf * 32 + q * 8;
            hb[kf] = *(const bf16x8*)(bsrc + b8 * 512 + ((2 * k0) ^ (b8 << 4)));
        }
#pragma unroll
        for (int j = 0; j < 4; ++j)
#pragma unroll
            for (int kf = 0; kf < 4; ++kf)
                acc[j] = mfma16(wf[j][kh * 4 + kf], hb[kf], acc[j]);
#pragma unroll
        for (int j = 4; j < 6; ++j)
#pragma unroll
            for (int kf = 0; kf < 4; ++kf) {
                bf16x8 a = *(const bf16x8*)(wlds +
                    (((w * 2 + (j - 4)) * 8 + kh * 4 + kf) << 10) + l * 16);
                acc[j] = mfma16(a, hb[kf], acc[j]);
            }
    }
}

// ---------------------------------------------------------------------------
// Chunk-granular 4-stage pipeline. 64 WGs x 512 thr: role = bid>>4, g=bid&15.
// Stages of group g sit at bids {g,16+g,32+g,48+g} == g (mod 8): under
// round-robin dispatch they share ONE XCD/L2. Payload: plain stores +
// vmcnt-drain on producer; volatile (sc0) loads on consumer -> coherent
// through the shared L2 with ZERO fences. Each pair verifies co-location
// via HW_REG_XCC_ID at startup; mismatched pairs fall back to agent fences
// (correct, slower). Flags: relaxed agent atomics, once per 64-step chunk.
// ---------------------------------------------------------------------------
__global__ __launch_bounds__(512, 2) void k_fused(
    const float* __restrict__ x, const float* __restrict__ hx,
    const float* __restrict__ W_ih, const float* __restrict__ W_hh,
    const float* __restrict__ gamma, const float* __restrict__ beta,
    float* __restrict__ Y, char* __restrict__ ws)
{
    extern __shared__ __align__(16) char lds[];
    const int bid = blockIdx.x;
    const int role = bid >> 4;
    const int g = bid & 15;
    const int layer = role >> 1;

    __bf16* ring0 = (__bf16*)ws;
    __bf16* ring1 = (__bf16*)(ws + (64u << 20));
    int* flagbase = (int*)(ws + (128u << 20));
#define FLAG(kind, gg) (flagbase + ((kind) * 16 + (gg)) * 32)   // kinds 0..7

    const int tid = threadIdx.x;
    const int w = tid >> 6, l = tid & 63;
    const int c = l & 15, q = l >> 4;
    const int b8 = c & 7, chi = c >> 3;

    char* wlds = lds;                        // 131072 B: W tiles j=4,5

    // ---- XCD exchange: post own id, read partners', decide fence need ----
    const int myx = get_xcc();
    if (tid == 0) publish(FLAG(4 + role, g), myx + 1);
    bool rem_p = false, rem_c = false;       // producer/consumer on other XCD?
    if (role > 0) {                          // has producer edge (payload in)
        int v = wait_ge(FLAG(4 + role - 1, g), 1);
        rem_p = ((v - 1) != myx);
    }
    if (role < 3) {                          // has consumer edge (payload out)
        int v = wait_ge(FLAG(4 + role + 1, g), 1);
        rem_c = ((v - 1) != myx);
    }

    if (!(role & 1)) {
        // ================= ih stages (role 0, 2) =================
        char* xst = lds + 131072;            // 4 x 4096 staging buffers
        const float* in = layer ? (const float*)Y : x;
        __bf16* ring = layer ? ring1 : ring0;
        int* p_self = FLAG(layer ? 2 : 0, g);
        int* p_dep  = layer ? FLAG(1, g) : nullptr;   // L0rec chunks (h0 ready)
        int* p_bp   = FLAG(layer ? 3 : 1, g);         // consumer rec chunks

        bf16x8 wf[4][8];
        load_wfrags(W_ih + (size_t)layer * GG * HH, wlds, wf, w, l, c, q);
        __syncthreads();

        const int stb = tid >> 6;            // batch 0..7
        const int stk = (tid & 63) * 4;      // k offset

#pragma unroll 1
        for (int k = 0; k < NC; ++k) {
            if (k >= 2) wait_ge(p_bp, k - 1);          // ring slot reuse safety
            if (p_dep) {
                wait_ge(p_dep, k + 1);
                if (rem_p) FENCE_ACQ();
            }
            const int t0 = k * CC;
#pragma unroll 1
            for (int q16 = 0; q16 < CC / 4; ++q16) {
                const int tq = t0 + q16 * 4;
#pragma unroll
                for (int kk = 0; kk < 4; ++kk) {
                    f32x4 v;
                    const float* sp = in +
                        ((size_t)(g * 8 + stb) * SS + tq + kk) * HH + stk;
                    if (layer) {             // h0 payload: sc0 loads via L2
                        u64 a0 = vld8((const u64*)sp);
                        u64 a1 = vld8((const u64*)sp + 1);
                        float2 f0 = __builtin_bit_cast(float2, a0);
                        float2 f1 = __builtin_bit_cast(float2, a1);
                        v = (f32x4){f0.x, f0.y, f1.x, f1.y};
                    } else {
                        v = *(const f32x4*)sp;
                    }
                    bf16x4 o;
#pragma unroll
                    for (int r = 0; r < 4; ++r) o[r] = (__bf16)v[r];
                    *(bf16x4*)(xst + kk * 4096 + stb * 512 +
                               ((2 * stk) ^ ((stb & 7) << 4))) = o;
                }
                LBAR();
#pragma unroll 1
                for (int kk = 0; kk < 4; ++kk) {
                    f32x4 acc[6];
#pragma unroll
                    for (int j = 0; j < 6; ++j) acc[j] = (f32x4){0.f, 0.f, 0.f, 0.f};
                    gemm6(acc, xst + kk * 4096, wlds, wf, w, l, q, b8);
                    if (c < 8) {
                        size_t base = ring_off(tq + kk, g, 0, b8, q * 4);
#pragma unroll
                        for (int j = 0; j < 6; ++j) {
                            bf16x4 o;
#pragma unroll
                            for (int r = 0; r < 4; ++r) o[r] = (__bf16)acc[j][r];
                            *(bf16x4*)(ring + base + (size_t)(w + 8 * j) * 128) = o;
                        }
                    }
                }
                LBAR();                       // protect xst for next quad
            }
            VBAR();                           // ring stores retired in L2
            if (rem_c) FENCE_REL();           // cross-XCD only
            if (tid == 0) publish(p_self, k + 1);
        }
    } else {
        // ================= rec stages (role 1, 3) =================
        char*  hbuf = lds + 131072;          // 4096: h[8][256] bf16 swz
        float* part = (float*)(lds + 135168);// 1920 B
        float* gb   = (float*)(lds + 137088);// 6144 B

        const __bf16* ring = layer ? ring1 : ring0;
        const float* gmm = gamma + (size_t)layer * GG;
        const float* bta = beta + (size_t)layer * GG;
        const float* hx0 = hx + (size_t)layer * BB * HH;
        int* p_src  = FLAG(layer ? 2 : 0, g);
        int* p_self = FLAG(layer ? 3 : 1, g);

        for (int idx = tid; idx < GG; idx += 512) {
            float sc = (idx >= 512) ? (-2.0f * LOG2E) : (-LOG2E);
            gb[idx]      = gmm[idx] * sc;
            gb[GG + idx] = bta[idx] * sc;
        }
        for (int idx = tid; idx < 8 * HH; idx += 512) {
            int b = idx >> 8, kk = idx & 255;
            *(__bf16*)(hbuf + b * 512 + ((2 * kk) ^ ((b & 7) << 4))) =
                (__bf16)hx0[(size_t)(g * 8 + b) * HH + kk];
        }
        bf16x8 wf[4][8];
        load_wfrags(W_hh + (size_t)layer * GG * HH, wlds, wf, w, l, c, q);
        __syncthreads();

        const int o0base = (w + 8 * chi) * 16 + q * 4;
        const int ho = w * 16 + chi * 128 + q * 4;
        float* yb = Y + (size_t)(g * 8 + b8) * SS * HH;

#pragma unroll 1
        for (int k = 0; k < NC; ++k) {
            wait_ge(p_src, k + 1);
            if (rem_p) FENCE_ACQ();
            const int t0 = k * CC;

            bf16x4 ihc[3], ihn[3];
            {
                size_t base = ring_off(t0, g, 0, b8, q * 4);
#pragma unroll
                for (int j2 = 0; j2 < 3; ++j2)
                    ihc[j2] = __builtin_bit_cast(bf16x4, vld8(
                        (const u64*)(ring + base + (size_t)(w + 8 * chi + 16 * j2) * 128)));
            }

#pragma unroll 1
            for (int tt = 0; tt < CC; ++tt) {
                const int t = t0 + tt;
                if (tt + 1 < CC) {             // in-chunk prefetch only
                    size_t base = ring_off(t + 1, g, 0, b8, q * 4);
#pragma unroll
                    for (int j2 = 0; j2 < 3; ++j2)
                        ihn[j2] = __builtin_bit_cast(bf16x4, vld8(
                            (const u64*)(ring + base + (size_t)(w + 8 * chi + 16 * j2) * 128)));
                }

                f32x4 acc[6];
#pragma unroll
                for (int j = 0; j < 6; ++j) acc[j] = (f32x4){0.f, 0.f, 0.f, 0.f};
                gemm6(acc, hbuf, wlds, wf, w, l, q, b8);

                // B-cols c and c^8 duplicate -> odd tiles already in acc[2j2+1]
                f32x4 pa[3];
#pragma unroll
                for (int j2 = 0; j2 < 3; ++j2)
                    pa[j2] = chi ? acc[2 * j2 + 1] : acc[2 * j2];

                // r,z stats
                float s0 = 0.f, t0s = 0.f, s1 = 0.f, t1 = 0.f;
#pragma unroll
                for (int r = 0; r < 4; ++r) {
                    float p0 = pa[0][r] + (float)ihc[0][r]; pa[0][r] = p0; s0 += p0; t0s += p0 * p0;
                    float p1 = pa[1][r] + (float)ihc[1][r]; pa[1][r] = p1; s1 += p1; t1 += p1 * p1;
                }
                s0 += __shfl_xor(s0, 16); t0s += __shfl_xor(t0s, 16);
                s0 += __shfl_xor(s0, 32); t0s += __shfl_xor(t0s, 32);
                s0 += __shfl_xor(s0, 8);  t0s += __shfl_xor(t0s, 8);
                s1 += __shfl_xor(s1, 16); t1 += __shfl_xor(t1, 16);
                s1 += __shfl_xor(s1, 32); t1 += __shfl_xor(t1, 32);
                s1 += __shfl_xor(s1, 8);  t1 += __shfl_xor(t1, 8);
                if (l < 8) {
                    *(float2*)(part + (0 * 8 + l) * 20 + w * 2) = make_float2(s0, t0s);
                    *(float2*)(part + (1 * 8 + l) * 20 + w * 2) = make_float2(s1, t1);
                }
                LBAR();  // BAR1

                float2 mrz[2];
#pragma unroll
                for (int gg = 0; gg < 2; ++gg) {
                    const f32x4* pp = (const f32x4*)(part + (gg * 8 + b8) * 20);
                    f32x4 a = pp[0] + pp[1] + pp[2] + pp[3];
                    float S = a[0] + a[2], Q2 = a[1] + a[3];
                    float m = S * (1.f / 256.f);
                    float v = Q2 * (1.f / 256.f) - m * m;
                    mrz[gg] = make_float2(m, __builtin_amdgcn_rsqf(v + 1e-5f));
                }

                float rz[2][4];
#pragma unroll
                for (int gg = 0; gg < 2; ++gg) {
                    int o0 = o0base + gg * 256;
                    f32x4 gam = *(f32x4*)(gb + o0);
                    f32x4 bet = *(f32x4*)(gb + GG + o0);
#pragma unroll
                    for (int r = 0; r < 4; ++r) {
                        float sf = mrz[gg].y * gam[r];
                        float y  = pa[gg][r] * sf + (bet[r] - mrz[gg].x * sf);
                        rz[gg][r] = __builtin_amdgcn_rcpf(1.f + __builtin_amdgcn_exp2f(y));
                    }
                }

                float pn[4]; float sn = 0.f, tn2 = 0.f;
#pragma unroll
                for (int r = 0; r < 4; ++r) {
                    float p = (float)ihc[2][r] + rz[0][r] * pa[2][r];
                    pn[r] = p; sn += p; tn2 += p * p;
                }
                sn += __shfl_xor(sn, 16); tn2 += __shfl_xor(tn2, 16);
                sn += __shfl_xor(sn, 32); tn2 += __shfl_xor(tn2, 32);
                sn += __shfl_xor(sn, 8);  tn2 += __shfl_xor(tn2, 8);
                if (l < 8)
                    *(float2*)(part + (2 * 8 + l) * 20 + w * 2) = make_float2(sn, tn2);
                LBAR();  // BAR2

                {
                    const f32x4* pp = (const f32x4*)(part + (2 * 8 + b8) * 20);
                    f32x4 a = pp[0] + pp[1] + pp[2] + pp[3];
                    float S = a[0] + a[2], Q2 = a[1] + a[3];
                    float m = S * (1.f / 256.f);
                    float v = Q2 * (1.f / 256.f) - m * m;
                    float rs = __builtin_amdgcn_rsqf(v + 1e-5f);

                    int o0 = o0base + 512;
                    f32x4 gam = *(f32x4*)(gb + o0);
                    f32x4 bet = *(f32x4*)(gb + GG + o0);
                    char* haddr = hbuf + b8 * 512 + ((2 * ho) ^ (b8 << 4));
                    bf16x4 hov = *(bf16x4*)haddr;
                    f32x4 yv; bf16x4 hnv;
#pragma unroll
                    for (int r = 0; r < 4; ++r) {
                        float sf = rs * gam[r];
                        float y  = pn[r] * sf + (bet[r] - m * sf);
                        float nh = 2.f * __builtin_amdgcn_rcpf(1.f + __builtin_amdgcn_exp2f(y)) - 1.f;
                        float hn = nh + rz[1][r] * ((float)hov[r] - nh);
                        yv[r] = hn; hnv[r] = (__bf16)hn;
                    }
                    *(bf16x4*)haddr = hnv;
                    *(f32x4*)(yb + (size_t)t * HH + ho) = yv;  // plain, drained per chunk
                }
                if (tt + 1 < CC) {
#pragma unroll
                    for (int j2 = 0; j2 < 3; ++j2) ihc[j2] = ihn[j2];
                }
                LBAR();  // BAR3 (protect hbuf for next gemm)
            }

            // chunk boundary: drain Y stores + ring reads into L2, then flag
            VBAR();
            if (layer == 0 && rem_c) FENCE_REL();   // cross-XCD h0 only
            if (tid == 0) publish(p_self, k + 1);
        }
    }
#undef FLAG
}

// ---------------------------------------------------------------------------
extern "C" void kernel_launch(void* const* d_in, const int* in_sizes, int n_in,
                              void* d_out, int out_size, void* d_ws, size_t ws_size,
                              hipStream_t stream)
{
    (void)in_sizes; (void)n_in; (void)out_size;
    const float* x    = (const float*)d_in[0];
    const float* hx   = (const float*)d_in[1];
    const float* W_ih = (const float*)d_in[2];
    const float* W_hh = (const float*)d_in[3];
    const float* gmm  = (const float*)d_in[4];
    const float* bta  = (const float*)d_in[5];
    float* Y = (float*)d_out;
    char* ws = (char*)d_ws;

    // ws: ring0 [0,25.2MB) ring1 [64MiB,+25.2MB) flags [128MiB,+32KB)
    if (ws_size < (size_t)SS * BB * GG * 2) return;

    hipFuncSetAttribute((const void*)k_fused,
                        hipFuncAttributeMaxDynamicSharedMemorySize, 147456);

    hipMemsetAsync(ws + (128u << 20), 0, 32768, stream);

    k_fused<<<dim3(64), dim3(512), 147456, stream>>>(
        x, hx, W_ih, W_hh, gmm, bta, Y, ws);
}

// Round 11
// 2733.338 us; speedup vs baseline: 6.9862x; 1.7837x over previous
//
#include <hip/hip_runtime.h>
#include <cstdint>

#define BB 128
#define SS 1024
#define HH 256
#define GG 768
#define CC 32                      // chunk length (timesteps)
#define NC (SS / CC)               // 32 chunks
#define DD 64                      // ring depth in slots = 2 chunks
#define LOG2E 1.44269504088896340736f

typedef __attribute__((ext_vector_type(8))) __bf16 bf16x8;
typedef __attribute__((ext_vector_type(4))) __bf16 bf16x4;
typedef __attribute__((ext_vector_type(4))) float f32x4;
typedef unsigned long long u64;

static __device__ __forceinline__ f32x4 mfma16(bf16x8 a, bf16x8 b, f32x4 c) {
    return __builtin_amdgcn_mfma_f32_16x16x32_bf16(a, b, c, 0, 0, 0);
}

static __device__ __forceinline__ bf16x8 load_w8(const float* __restrict__ p) {
    f32x4 a = *(const f32x4*)p;
    f32x4 b = *(const f32x4*)(p + 4);
    bf16x8 v;
    v[0] = (__bf16)a[0]; v[1] = (__bf16)a[1]; v[2] = (__bf16)a[2]; v[3] = (__bf16)a[3];
    v[4] = (__bf16)b[0]; v[5] = (__bf16)b[1]; v[6] = (__bf16)b[2]; v[7] = (__bf16)b[3];
    return v;
}

// LDS-only barrier (global ops keep floating) / full-drain barrier
#define LBAR() asm volatile("s_waitcnt lgkmcnt(0)\n\ts_barrier" ::: "memory")
#define VBAR() asm volatile("s_waitcnt vmcnt(0) lgkmcnt(0)\n\ts_barrier" ::: "memory")
// per-chunk coherence (amortized 32x)
#define FENCE_ACQ() __builtin_amdgcn_fence(__ATOMIC_ACQUIRE, "agent")
#define FENCE_REL() __builtin_amdgcn_fence(__ATOMIC_RELEASE, "agent")

// ih-ring element offset: slot-major, tile T=0..47, 8 batches x 16 outs
static __device__ __forceinline__ size_t ring_off(int t, int g, int T, int b8, int o) {
    return (((size_t)(t & (DD - 1)) * 16 + g) * 48 + T) * 128 + b8 * 16 + o;
}
// h0-ring slot byte offset (4KB per (t,g), hbuf-swizzled layout inside)
static __device__ __forceinline__ size_t hslot(int t, int g) {
    return ((size_t)(t & (DD - 1)) * 16 + g) << 12;
}

static __device__ __forceinline__ int ldflag(int* p) {
    return __hip_atomic_load(p, __ATOMIC_RELAXED, __HIP_MEMORY_SCOPE_AGENT);
}
static __device__ __forceinline__ void wait_ge(int* p, int need) {
    int v = ldflag(p);
    while (v < need) {
        __builtin_amdgcn_s_sleep(8);
        v = ldflag(p);
    }
}
static __device__ __forceinline__ void publish(int* p, int v) {
    __hip_atomic_store(p, v, __ATOMIC_RELAXED, __HIP_MEMORY_SCOPE_AGENT);
}

// wave w holds W tiles w+8j: j=0..3 in VGPR, j=4,5 staged to LDS
static __device__ __forceinline__ void load_wfrags(
    const float* __restrict__ W, char* wlds, bf16x8 (&wf)[4][8],
    int w, int l, int c, int q)
{
#pragma unroll
    for (int j = 0; j < 4; ++j) {
        const float* wp = W + (size_t)((w + 8 * j) * 16 + c) * HH + q * 8;
#pragma unroll
        for (int kf = 0; kf < 8; ++kf) wf[j][kf] = load_w8(wp + kf * 32);
    }
#pragma unroll
    for (int j = 4; j < 6; ++j) {
        const float* wp = W + (size_t)((w + 8 * j) * 16 + c) * HH + q * 8;
#pragma unroll
        for (int kf = 0; kf < 8; ++kf) {
            bf16x8 v = load_w8(wp + kf * 32);
            *(bf16x8*)(wlds + (((w * 2 + (j - 4)) * 8 + kf) << 10) + l * 16) = v;
        }
    }
}

// 48 MFMAs/wave over K=256 from swizzled LDS B-buffer (8 rows x 256 bf16).
// Ordered j=0..3 (VGPR A) first, j=4,5 (LDS A) last so the r/z statistics
// (which only need acc[0..3]) can overlap the in-flight n-tile MFMAs.
static __device__ __forceinline__ void gemm6(
    f32x4 (&acc)[6], const char* bsrc, const char* wlds,
    const bf16x8 (&wf)[4][8], int w, int l, int q, int b8)
{
    bf16x8 hb[2][4];
#pragma unroll
    for (int kh = 0; kh < 2; ++kh)
#pragma unroll
        for (int kf = 0; kf < 4; ++kf) {
            int k0 = kh * 128 + kf * 32 + q * 8;
            hb[kh][kf] = *(const bf16x8*)(bsrc + b8 * 512 + ((2 * k0) ^ (b8 << 4)));
        }
#pragma unroll
    for (int j = 0; j < 4; ++j)
#pragma unroll
        for (int kh = 0; kh < 2; ++kh)
#pragma unroll
            for (int kf = 0; kf < 4; ++kf)
                acc[j] = mfma16(wf[j][kh * 4 + kf], hb[kh][kf], acc[j]);
#pragma unroll
    for (int j = 4; j < 6; ++j)
#pragma unroll
        for (int kh = 0; kh < 2; ++kh)
#pragma unroll
            for (int kf = 0; kf < 4; ++kf) {
                bf16x8 a = *(const bf16x8*)(wlds +
                    (((w * 2 + (j - 4)) * 8 + kh * 4 + kf) << 10) + l * 16);
                acc[j] = mfma16(a, hb[kh][kf], acc[j]);
            }
}

// ---------------------------------------------------------------------------
// Chunk-granular 4-stage pipeline (C=32). 64 WGs x 512 thr: role=bid>>4,
// g=bid&15.
//   role 0: L0ih (x -> ring0)      role 1: L0rec (ring0 -> hring, bf16 swz)
//   role 2: L1ih (hring -> ring1)  role 3: L1rec (ring1 -> Y, fp32)
// L0rec does NOT write Y (d_out carries only h1). All payload plain
// loads/stores; coherence once per chunk (VBAR + REL / wait + ACQ).
// LDS budget (FIX vs r10): ih roles use xst at 131072 (+16KB = 147456 max);
// rec roles end at 143232. Dynamic LDS = 147456.
// ---------------------------------------------------------------------------
__global__ __launch_bounds__(512, 2) void k_fused(
    const float* __restrict__ x, const float* __restrict__ hx,
    const float* __restrict__ W_ih, const float* __restrict__ W_hh,
    const float* __restrict__ gamma, const float* __restrict__ beta,
    float* __restrict__ Y, char* __restrict__ ws)
{
    extern __shared__ __align__(16) char lds[];
    const int bid = blockIdx.x;
    const int role = bid >> 4;
    const int g = bid & 15;
    const int layer = role >> 1;

    __bf16* ring0 = (__bf16*)ws;
    __bf16* ring1 = (__bf16*)(ws + (32u << 20));
    char*   hring = ws + (64u << 20);
    int* flagbase = (int*)(ws + (128u << 20));
#define FLAG(kind, gg) (flagbase + ((kind) * 16 + (gg)) * 32)

    const int tid = threadIdx.x;
    const int w = tid >> 6, l = tid & 63;
    const int c = l & 15, q = l >> 4;
    const int b8 = c & 7, chi = c >> 3;

    char* wlds = lds;                        // 131072 B: W tiles j=4,5

    if (role == 0) {
        // ============ L0ih: x -> ring0, 4 steps per staging round ============
        char* xst = lds + 131072;            // 4 x 4096 staging buffers
        int* p_self = FLAG(0, g);
        int* p_bp   = FLAG(1, g);

        bf16x8 wf[4][8];
        load_wfrags(W_ih, wlds, wf, w, l, c, q);
        __syncthreads();

        const int stb = tid >> 6;            // batch 0..7
        const int stk = (tid & 63) * 4;      // k offset (elements)

#pragma unroll 1
        for (int k = 0; k < NC; ++k) {
            if (k >= 2) wait_ge(p_bp, k - 1);          // ring slot reuse
            const int t0 = k * CC;
#pragma unroll 1
            for (int q16 = 0; q16 < CC / 4; ++q16) {
                const int tq = t0 + q16 * 4;
#pragma unroll
                for (int kk = 0; kk < 4; ++kk) {
                    f32x4 v = *(const f32x4*)(x +
                        ((size_t)(g * 8 + stb) * SS + tq + kk) * HH + stk);
                    bf16x4 o;
#pragma unroll
                    for (int r = 0; r < 4; ++r) o[r] = (__bf16)v[r];
                    *(bf16x4*)(xst + kk * 4096 + stb * 512 +
                               ((2 * stk) ^ ((stb & 7) << 4))) = o;
                }
                LBAR();
#pragma unroll 1
                for (int kk = 0; kk < 4; ++kk) {
                    f32x4 acc[6];
#pragma unroll
                    for (int j = 0; j < 6; ++j) acc[j] = (f32x4){0.f, 0.f, 0.f, 0.f};
                    gemm6(acc, xst + kk * 4096, wlds, wf, w, l, q, b8);
                    if (c < 8) {
                        size_t base = ring_off(tq + kk, g, 0, b8, q * 4);
#pragma unroll
                        for (int j = 0; j < 6; ++j) {
                            bf16x4 o;
#pragma unroll
                            for (int r = 0; r < 4; ++r) o[r] = (__bf16)acc[j][r];
                            *(bf16x4*)(ring0 + base + (size_t)(w + 8 * j) * 128) = o;
                        }
                    }
                }
                LBAR();                       // protect xst
            }
            VBAR();
            FENCE_REL();
            if (tid == 0) publish(p_self, k + 1);
        }
    } else if (role == 2) {
        // ============ L1ih: hring -> ring1, 2 steps per round ============
        char* xst = lds + 131072;            // 2 x 4096
        int* p_self = FLAG(2, g);
        int* p_dep  = FLAG(1, g);            // L0rec chunks (h0 ready)
        int* p_bp   = FLAG(3, g);            // L1rec chunks (ring1 reuse)

        bf16x8 wf[4][8];
        load_wfrags(W_ih + (size_t)GG * HH, wlds, wf, w, l, c, q);
        __syncthreads();

        const int ct = tid >> 8;             // which of the 2 steps to copy
        const int co = (tid & 255) * 16;     // byte offset within 4KB slot

#pragma unroll 1
        for (int k = 0; k < NC; ++k) {
            if (k >= 2) wait_ge(p_bp, k - 1);
            wait_ge(p_dep, k + 1);
            FENCE_ACQ();
            const int t0 = k * CC;
#pragma unroll 1
            for (int p2 = 0; p2 < CC / 2; ++p2) {
                const int u = t0 + p2 * 2;
                // pure copy: hring slots are already bf16 + hbuf-swizzled
                {
                    bf16x8 v = *(const bf16x8*)(hring + hslot(u + ct, g) + co);
                    *(bf16x8*)(xst + ct * 4096 + co) = v;
                }
                LBAR();
#pragma unroll 1
                for (int kk = 0; kk < 2; ++kk) {
                    f32x4 acc[6];
#pragma unroll
                    for (int j = 0; j < 6; ++j) acc[j] = (f32x4){0.f, 0.f, 0.f, 0.f};
                    gemm6(acc, xst + kk * 4096, wlds, wf, w, l, q, b8);
                    if (c < 8) {
                        size_t base = ring_off(u + kk, g, 0, b8, q * 4);
#pragma unroll
                        for (int j = 0; j < 6; ++j) {
                            bf16x4 o;
#pragma unroll
                            for (int r = 0; r < 4; ++r) o[r] = (__bf16)acc[j][r];
                            *(bf16x4*)(ring1 + base + (size_t)(w + 8 * j) * 128) = o;
                        }
                    }
                }
                LBAR();                       // protect xst
            }
            VBAR();
            FENCE_REL();
            if (tid == 0) publish(p_self, k + 1);
        }
    } else {
        // ================= rec stages (role 1, 3) =================
        char*  hbuf = lds + 131072;          // 4096: h[8][256] bf16 swz
        float* part = (float*)(lds + 135168);// 1920 B
        float* gb   = (float*)(lds + 137088);// 6144 B -> ends 143232

        const __bf16* ring = layer ? ring1 : ring0;
        const float* gmm = gamma + (size_t)layer * GG;
        const float* bta = beta + (size_t)layer * GG;
        const float* hx0 = hx + (size_t)layer * BB * HH;
        int* p_src  = FLAG(layer ? 2 : 0, g);
        int* p_self = FLAG(layer ? 3 : 1, g);
        int* p_hbp  = FLAG(2, g);            // L1ih progress (hring reuse, L0 only)

        for (int idx = tid; idx < GG; idx += 512) {
            float sc = (idx >= 512) ? (-2.0f * LOG2E) : (-LOG2E);
            gb[idx]      = gmm[idx] * sc;
            gb[GG + idx] = bta[idx] * sc;
        }
        for (int idx = tid; idx < 8 * HH; idx += 512) {
            int b = idx >> 8, kk = idx & 255;
            *(__bf16*)(hbuf + b * 512 + ((2 * kk) ^ ((b & 7) << 4))) =
                (__bf16)hx0[(size_t)(g * 8 + b) * HH + kk];
        }
        bf16x8 wf[4][8];
        load_wfrags(W_hh + (size_t)layer * GG * HH, wlds, wf, w, l, c, q);
        __syncthreads();

        const int o0base = (w + 8 * chi) * 16 + q * 4;
        const int ho = w * 16 + chi * 128 + q * 4;
        float* yb = Y + (size_t)(g * 8 + b8) * SS * HH;

#pragma unroll 1
        for (int k = 0; k < NC; ++k) {
            wait_ge(p_src, k + 1);
            if (layer == 0 && k >= 2) wait_ge(p_hbp, k - 1);  // hring reuse
            FENCE_ACQ();
            const int t0 = k * CC;

            bf16x4 ihc[3], ihn[3];
            {
                size_t base = ring_off(t0, g, 0, b8, q * 4);
#pragma unroll
                for (int j2 = 0; j2 < 3; ++j2)
                    ihc[j2] = *(const bf16x4*)(ring + base +
                        (size_t)(w + 8 * chi + 16 * j2) * 128);
            }

#pragma unroll 1
            for (int tt = 0; tt < CC; ++tt) {
                const int t = t0 + tt;
                if (tt + 1 < CC) {             // in-chunk prefetch
                    size_t base = ring_off(t + 1, g, 0, b8, q * 4);
#pragma unroll
                    for (int j2 = 0; j2 < 3; ++j2)
                        ihn[j2] = *(const bf16x4*)(ring + base +
                            (size_t)(w + 8 * chi + 16 * j2) * 128);
                }

                f32x4 acc[6];
#pragma unroll
                for (int j = 0; j < 6; ++j) acc[j] = (f32x4){0.f, 0.f, 0.f, 0.f};
                gemm6(acc, hbuf, wlds, wf, w, l, q, b8);

                // B-cols c and c^8 duplicate -> odd tiles already in acc[2j2+1]
                f32x4 pa0 = chi ? acc[1] : acc[0];
                f32x4 pa1 = chi ? acc[3] : acc[2];

                // r,z stats (only needs acc[0..3]; n MFMAs may still be in pipe)
                float s0 = 0.f, t0s = 0.f, s1 = 0.f, t1 = 0.f;
#pragma unroll
                for (int r = 0; r < 4; ++r) {
                    float p0 = pa0[r] + (float)ihc[0][r]; pa0[r] = p0; s0 += p0; t0s += p0 * p0;
                    float p1 = pa1[r] + (float)ihc[1][r]; pa1[r] = p1; s1 += p1; t1 += p1 * p1;
                }
                s0 += __shfl_xor(s0, 16); t0s += __shfl_xor(t0s, 16);
                s0 += __shfl_xor(s0, 32); t0s += __shfl_xor(t0s, 32);
                s0 += __shfl_xor(s0, 8);  t0s += __shfl_xor(t0s, 8);
                s1 += __shfl_xor(s1, 16); t1 += __shfl_xor(t1, 16);
                s1 += __shfl_xor(s1, 32); t1 += __shfl_xor(t1, 32);
                s1 += __shfl_xor(s1, 8);  t1 += __shfl_xor(t1, 8);
                if (l < 8) {
                    *(float2*)(part + (0 * 8 + l) * 20 + w * 2) = make_float2(s0, t0s);
                    *(float2*)(part + (1 * 8 + l) * 20 + w * 2) = make_float2(s1, t1);
                }
                LBAR();  // BAR1

                // chi-split mu/rstd: chi=0 lanes compute gate r, chi=1 gate z,
                // then exchange across the pair with 2 shfl_xor.
                float2 mrz[2];
                {
                    const f32x4* pp = (const f32x4*)(part + (chi * 8 + b8) * 20);
                    f32x4 a = pp[0] + pp[1] + pp[2] + pp[3];
                    float S = a[0] + a[2], Q2 = a[1] + a[3];
                    float m = S * (1.f / 256.f);
                    float v = Q2 * (1.f / 256.f) - m * m;
                    float rs = __builtin_amdgcn_rsqf(v + 1e-5f);
                    float mo = __shfl_xor(m, 8);
                    float rso = __shfl_xor(rs, 8);
                    mrz[0] = chi ? make_float2(mo, rso) : make_float2(m, rs);
                    mrz[1] = chi ? make_float2(m, rs) : make_float2(mo, rso);
                }

                float rz[2][4];
#pragma unroll
                for (int gg = 0; gg < 2; ++gg) {
                    int o0 = o0base + gg * 256;
                    f32x4 gam = *(f32x4*)(gb + o0);
                    f32x4 bet = *(f32x4*)(gb + GG + o0);
                    f32x4 pag = gg ? pa1 : pa0;
#pragma unroll
                    for (int r = 0; r < 4; ++r) {
                        float sf = mrz[gg].y * gam[r];
                        float y  = pag[r] * sf + (bet[r] - mrz[gg].x * sf);
                        rz[gg][r] = __builtin_amdgcn_rcpf(1.f + __builtin_amdgcn_exp2f(y));
                    }
                }

                f32x4 pa2 = chi ? acc[5] : acc[4];
                float pn[4]; float sn = 0.f, tn2 = 0.f;
#pragma unroll
                for (int r = 0; r < 4; ++r) {
                    float p = (float)ihc[2][r] + rz[0][r] * pa2[r];
                    pn[r] = p; sn += p; tn2 += p * p;
                }
                sn += __shfl_xor(sn, 16); tn2 += __shfl_xor(tn2, 16);
                sn += __shfl_xor(sn, 32); tn2 += __shfl_xor(tn2, 32);
                sn += __shfl_xor(sn, 8);  tn2 += __shfl_xor(tn2, 8);
                if (l < 8)
                    *(float2*)(part + (2 * 8 + l) * 20 + w * 2) = make_float2(sn, tn2);
                LBAR();  // BAR2

                {
                    const f32x4* pp = (const f32x4*)(part + (2 * 8 + b8) * 20);
                    f32x4 a = pp[0] + pp[1] + pp[2] + pp[3];
                    float S = a[0] + a[2], Q2 = a[1] + a[3];
                    float m = S * (1.f / 256.f);
                    float v = Q2 * (1.f / 256.f) - m * m;
                    float rs = __builtin_amdgcn_rsqf(v + 1e-5f);

                    int o0 = o0base + 512;
                    f32x4 gam = *(f32x4*)(gb + o0);
                    f32x4 bet = *(f32x4*)(gb + GG + o0);
                    char* haddr = hbuf + b8 * 512 + ((2 * ho) ^ (b8 << 4));
                    bf16x4 hov = *(bf16x4*)haddr;
                    f32x4 yv; bf16x4 hnv;
#pragma unroll
                    for (int r = 0; r < 4; ++r) {
                        float sf = rs * gam[r];
                        float y  = pn[r] * sf + (bet[r] - m * sf);
                        float nh = 2.f * __builtin_amdgcn_rcpf(1.f + __builtin_amdgcn_exp2f(y)) - 1.f;
                        float hn = nh + rz[1][r] * ((float)hov[r] - nh);
                        yv[r] = hn; hnv[r] = (__bf16)hn;
                    }
                    *(bf16x4*)haddr = hnv;
                    if (layer == 0) {
                        // h0 -> hring in the exact hbuf-swizzled layout
                        *(bf16x4*)(hring + hslot(t, g) + b8 * 512 +
                                   ((2 * ho) ^ (b8 << 4))) = hnv;
                    } else {
                        *(f32x4*)(yb + (size_t)t * HH + ho) = yv;  // final output
                    }
                }
                if (tt + 1 < CC) {
#pragma unroll
                    for (int j2 = 0; j2 < 3; ++j2) ihc[j2] = ihn[j2];
                }
                LBAR();  // BAR3 (protect hbuf)
            }

            VBAR();
            if (layer == 0) FENCE_REL();     // hring chunk -> visible to L1ih
            if (tid == 0) publish(p_self, k + 1);
        }
    }
#undef FLAG
}

// ---------------------------------------------------------------------------
extern "C" void kernel_launch(void* const* d_in, const int* in_sizes, int n_in,
                              void* d_out, int out_size, void* d_ws, size_t ws_size,
                              hipStream_t stream)
{
    (void)in_sizes; (void)n_in; (void)out_size;
    const float* x    = (const float*)d_in[0];
    const float* hx   = (const float*)d_in[1];
    const float* W_ih = (const float*)d_in[2];
    const float* W_hh = (const float*)d_in[3];
    const float* gmm  = (const float*)d_in[4];
    const float* bta  = (const float*)d_in[5];
    float* Y = (float*)d_out;
    char* ws = (char*)d_ws;

    // ws: ring0 [0,12.6MB) ring1 [32MiB,+12.6MB) hring [64MiB,+4MiB)
    //     flags [128MiB,+32KB)
    if (ws_size < (size_t)SS * BB * GG * 2) return;

    hipFuncSetAttribute((const void*)k_fused,
                        hipFuncAttributeMaxDynamicSharedMemorySize, 147456);

    hipMemsetAsync(ws + (128u << 20), 0, 32768, stream);

    k_fused<<<dim3(64), dim3(512), 147456, stream>>>(
        x, hx, W_ih, W_hh, gmm, bta, Y, ws);
}